// Round 1
// 856.401 us; speedup vs baseline: 1.0546x; 1.0546x over previous
//
#include <hip/hip_runtime.h>
#include <math.h>

#define B_ 64
#define N_ 16384
#define M_ 128
#define C_ 1024
#define EPS_ 1e-16f

__device__ __forceinline__ float softplus_(float x) {
    return fmaxf(x, 0.f) + log1pf(expf(-fabsf(x)));
}

// ---------------------------------------------------------------------------
// Kernel A: parameter projections + zero-init of sums and read_vec output.
// One block per batch, 128 threads. erase/add are unused -> skipped.
// ---------------------------------------------------------------------------
__global__ void proj_kernel(const float* __restrict__ ctrl,
                            const float* __restrict__ key_w, const float* __restrict__ key_b,
                            const float* __restrict__ beta_w, const float* __restrict__ beta_b,
                            const float* __restrict__ gate_w, const float* __restrict__ gate_b,
                            const float* __restrict__ shift_w, const float* __restrict__ shift_b,
                            const float* __restrict__ gamma_w, const float* __restrict__ gamma_b,
                            float* __restrict__ k_out, float* __restrict__ kn_out,
                            float* __restrict__ beta_out, float* __restrict__ gate_out,
                            float* __restrict__ gamma_out, float* __restrict__ shift_out,
                            float* __restrict__ sumE, float* __restrict__ sumWp,
                            float* __restrict__ read_out)
{
    const int b = blockIdx.x;
    const int t = threadIdx.x;            // 128 threads, one per m
    const float* c = ctrl + (size_t)b * C_;

    // zero-init (replaces hipMemsetAsync calls)
    read_out[b * M_ + t] = 0.f;
    if (t == 0) { sumE[b] = 0.f; sumWp[b] = 0.f; }

    // key projection: 4-way ILP to break the serial FMA chain
    float a0 = 0.f, a1 = 0.f, a2 = 0.f, a3 = 0.f;
    for (int i = 0; i < C_; i += 4) {
        a0 = fmaf(c[i+0], key_w[(i+0) * M_ + t], a0);
        a1 = fmaf(c[i+1], key_w[(i+1) * M_ + t], a1);
        a2 = fmaf(c[i+2], key_w[(i+2) * M_ + t], a2);
        a3 = fmaf(c[i+3], key_w[(i+3) * M_ + t], a3);
    }
    float kv = tanhf(((a0 + a1) + (a2 + a3)) + key_b[t]);
    k_out[b * M_ + t] = kv;

    float p0 = 0, p1 = 0, p2 = 0, p3 = 0, p4 = 0, p5 = 0;
    for (int i = t; i < C_; i += 128) {
        float cv = c[i];
        p0 = fmaf(cv, beta_w[i],      p0);
        p1 = fmaf(cv, gate_w[i],      p1);
        p2 = fmaf(cv, gamma_w[i],     p2);
        p3 = fmaf(cv, shift_w[3*i+0], p3);
        p4 = fmaf(cv, shift_w[3*i+1], p4);
        p5 = fmaf(cv, shift_w[3*i+2], p5);
    }
    __shared__ float red[7][128];
    red[0][t] = p0; red[1][t] = p1; red[2][t] = p2;
    red[3][t] = p3; red[4][t] = p4; red[5][t] = p5;
    red[6][t] = kv * kv;
    __syncthreads();
    for (int s = 64; s > 0; s >>= 1) {
        if (t < s) {
            #pragma unroll
            for (int j = 0; j < 7; ++j) red[j][t] += red[j][t + s];
        }
        __syncthreads();
    }
    if (t == 0) {
        beta_out[b]  = softplus_(red[0][0] + beta_b[0]);
        gate_out[b]  = 1.f / (1.f + expf(-(red[1][0] + gate_b[0])));
        gamma_out[b] = 1.f + softplus_(red[2][0] + gamma_b[0]);
        float z0 = red[3][0] + shift_b[0];
        float z1 = red[4][0] + shift_b[1];
        float z2 = red[5][0] + shift_b[2];
        float mx = fmaxf(z0, fmaxf(z1, z2));
        float e0 = expf(z0 - mx), e1 = expf(z1 - mx), e2 = expf(z2 - mx);
        float inv = 1.f / (e0 + e1 + e2);
        shift_out[b*3+0] = e0 * inv;
        shift_out[b*3+1] = e1 * inv;
        shift_out[b*3+2] = e2 * inv;
        kn_out[b] = sqrtf(red[6][0]);
    }
}

// ---------------------------------------------------------------------------
// Kernel B: content addressing, 8-row x 8-lane layout.
// Each wave covers 8 consecutive rows; lane (r,c) accumulates dot and
// sum-of-squares over 16 elements of row r (4 float4 windows 128B apart).
// Cross-lane reduce is only 3 shuffle levels (within the 8 c-lanes), and the
// div/sqrt/exp tail runs once per 8 rows (redundantly across c-lanes, free).
// e = exp(beta/||k|| * d * rsqrt(q)); EPS is negligible vs norms ~O(100).
// ---------------------------------------------------------------------------
#define ROWS_PER_CHUNK 1024
__global__ void content_kernel(const float* __restrict__ mem,
                               const float* __restrict__ k,
                               const float* __restrict__ kn,
                               const float* __restrict__ beta,
                               float* __restrict__ e_out,
                               float* __restrict__ sumE)
{
    const int b     = blockIdx.y;
    const int chunk = blockIdx.x;
    const int t     = threadIdx.x;        // 256 threads = 4 waves
    const int wave  = t >> 6;
    const int lane  = t & 63;
    const int r     = lane >> 3;          // 8 rows per wave
    const int c     = lane & 7;           // 8 lanes per row

    __shared__ float ks[M_];
    if (t < M_) ks[t] = k[b * M_ + t];
    __syncthreads();
    const float4 kf0 = reinterpret_cast<const float4*>(ks)[c];
    const float4 kf1 = reinterpret_cast<const float4*>(ks)[c + 8];
    const float4 kf2 = reinterpret_cast<const float4*>(ks)[c + 16];
    const float4 kf3 = reinterpret_cast<const float4*>(ks)[c + 24];
    const float bk = beta[b] / kn[b];

    const float* memb = mem + (size_t)b * N_ * M_;
    const int row0 = chunk * ROWS_PER_CHUNK + wave * 8 + r;

    float eacc = 0.f;
    #pragma unroll 2
    for (int tile = 0; tile < 32; ++tile) {
        const int row = row0 + tile * 32;
        const float4* mrow = reinterpret_cast<const float4*>(memb + (size_t)row * M_);
        float4 m;
        m = mrow[c];
        float d = m.x*kf0.x + m.y*kf0.y + m.z*kf0.z + m.w*kf0.w;
        float q = m.x*m.x + m.y*m.y + m.z*m.z + m.w*m.w;
        m = mrow[c + 8];
        d += m.x*kf1.x + m.y*kf1.y + m.z*kf1.z + m.w*kf1.w;
        q += m.x*m.x + m.y*m.y + m.z*m.z + m.w*m.w;
        m = mrow[c + 16];
        d += m.x*kf2.x + m.y*kf2.y + m.z*kf2.z + m.w*kf2.w;
        q += m.x*m.x + m.y*m.y + m.z*m.z + m.w*m.w;
        m = mrow[c + 24];
        d += m.x*kf3.x + m.y*kf3.y + m.z*kf3.z + m.w*kf3.w;
        q += m.x*m.x + m.y*m.y + m.z*m.z + m.w*m.w;
        // butterfly over the 8 c-lanes (xor 1,2,4 stays inside the group)
        d += __shfl_xor(d, 1, 64);  q += __shfl_xor(q, 1, 64);
        d += __shfl_xor(d, 2, 64);  q += __shfl_xor(q, 2, 64);
        d += __shfl_xor(d, 4, 64);  q += __shfl_xor(q, 4, 64);
        const float ev = __expf(bk * d * rsqrtf(q));
        if (c == 0) {
            e_out[(size_t)b * N_ + row] = ev;
            eacc += ev;
        }
    }
    __shared__ float red[256];
    red[t] = eacc;
    __syncthreads();
    for (int s = 128; s > 0; s >>= 1) {
        if (t < s) red[t] += red[t + s];
        __syncthreads();
    }
    if (t == 0) atomicAdd(&sumE[b], red[0]);
}

// ---------------------------------------------------------------------------
// Kernel C: gated interpolation + circular 3-tap shift + sharpen (pow).
// float4-vectorized: each thread produces 4 outputs; only the two edge
// neighbors need extra scalar loads (L1/L2 hits).
// ---------------------------------------------------------------------------
__global__ void shiftpow_kernel(const float* __restrict__ e,
                                const float* __restrict__ prev,
                                const float* __restrict__ sumE,
                                const float* __restrict__ gate,
                                const float* __restrict__ shift,
                                const float* __restrict__ gamma,
                                float* __restrict__ wp_out,
                                float* __restrict__ sumWp)
{
    const int b = blockIdx.y;
    const int i = blockIdx.x * 256 + threadIdx.x;   // float4 index over N/4
    const float invE = 1.f / sumE[b];               // jax softmax: no eps in denom
    const float g    = gate[b];
    const float gi   = g * invE;
    const float om   = 1.f - g;
    const float s0 = shift[b*3+0], s1 = shift[b*3+1], s2 = shift[b*3+2];
    const float gam = gamma[b];
    const float* eb = e    + (size_t)b * N_;
    const float* pb = prev + (size_t)b * N_;

    const float4 ec = reinterpret_cast<const float4*>(eb)[i];
    const float4 pc = reinterpret_cast<const float4*>(pb)[i];
    const int il = (i == 0)          ? N_ - 1 : 4*i - 1;   // wrap left
    const int ir = (i == N_/4 - 1)   ? 0      : 4*i + 4;   // wrap right
    const float wl = gi*eb[il] + om*pb[il];
    const float w0 = gi*ec.x  + om*pc.x;
    const float w1 = gi*ec.y  + om*pc.y;
    const float w2 = gi*ec.z  + om*pc.z;
    const float w3 = gi*ec.w  + om*pc.w;
    const float wr = gi*eb[ir] + om*pb[ir];

    float4 o;
    o.x = powf(s0*wl + s1*w0 + s2*w1, gam);
    o.y = powf(s0*w0 + s1*w1 + s2*w2, gam);
    o.z = powf(s0*w1 + s1*w2 + s2*w3, gam);
    o.w = powf(s0*w2 + s1*w3 + s2*wr, gam);
    reinterpret_cast<float4*>(wp_out + (size_t)b * N_)[i] = o;

    __shared__ float red[256];
    red[threadIdx.x] = (o.x + o.y) + (o.z + o.w);
    __syncthreads();
    for (int s = 128; s > 0; s >>= 1) {
        if (threadIdx.x < s) red[threadIdx.x] += red[threadIdx.x + s];
        __syncthreads();
    }
    if (threadIdx.x == 0) atomicAdd(&sumWp[b], red[0]);
}

// ---------------------------------------------------------------------------
// Kernel D (fused normalize + read): stages raw wp for the chunk in LDS and
// writes the normalized weights output during staging; accumulates
// sum(wp_n * mem_n) per lane, scales by 1/(sumWp+eps) at the end, LDS-reduces
// across the 8 row-groups, atomicAdd partial into read_vec.
// ---------------------------------------------------------------------------
__global__ void read_kernel(const float* __restrict__ mem,
                            const float* __restrict__ wp,
                            const float* __restrict__ sumWp,
                            float* __restrict__ out_w,
                            float* __restrict__ read_out)
{
    const int b     = blockIdx.y;
    const int chunk = blockIdx.x;
    const int t     = threadIdx.x;        // 256
    const int wave  = t >> 6;
    const int lane  = t & 63;
    const int half  = lane >> 5;
    const int sub   = lane & 31;
    const float inv = 1.f / (sumWp[b] + EPS_);

    __shared__ float wtile[ROWS_PER_CHUNK];
    {
        const float4 v = reinterpret_cast<const float4*>(
            wp + (size_t)b * N_ + chunk * ROWS_PER_CHUNK)[t];
        reinterpret_cast<float4*>(wtile)[t] = v;
        float4 o;
        o.x = v.x * inv; o.y = v.y * inv; o.z = v.z * inv; o.w = v.w * inv;
        reinterpret_cast<float4*>(
            out_w + (size_t)b * N_ + chunk * ROWS_PER_CHUNK)[t] = o;   // fused normalize
    }
    __syncthreads();

    const float* memb = mem + (size_t)b * N_ * M_;
    const int rowbase = chunk * ROWS_PER_CHUNK + wave * 2 + half;
    const int lbase   = wave * 2 + half;

    float4 acc = make_float4(0.f, 0.f, 0.f, 0.f);
    #pragma unroll 4
    for (int i = 0; i < ROWS_PER_CHUNK / 8; ++i) {
        const int n  = rowbase + i * 8;
        const float wn = wtile[lbase + i * 8];          // LDS broadcast
        const float4 m4 = reinterpret_cast<const float4*>(memb + (size_t)n * M_)[sub];
        acc.x = fmaf(wn, m4.x, acc.x);
        acc.y = fmaf(wn, m4.y, acc.y);
        acc.z = fmaf(wn, m4.z, acc.z);
        acc.w = fmaf(wn, m4.w, acc.w);
    }
    acc.x *= inv; acc.y *= inv; acc.z *= inv; acc.w *= inv;

    __shared__ float red[8][32][4];
    const int g = wave * 2 + half;
    red[g][sub][0] = acc.x; red[g][sub][1] = acc.y;
    red[g][sub][2] = acc.z; red[g][sub][3] = acc.w;
    __syncthreads();
    if (t < M_) {
        const int m = t, s2 = m >> 2, cc = m & 3;
        float s = 0.f;
        #pragma unroll
        for (int gg = 0; gg < 8; ++gg) s += red[gg][s2][cc];
        atomicAdd(&read_out[b * M_ + m], s);
    }
}

// ---------------------------------------------------------------------------
extern "C" void kernel_launch(void* const* d_in, const int* in_sizes, int n_in,
                              void* d_out, int out_size, void* d_ws, size_t ws_size,
                              hipStream_t stream) {
    const float* ctrl    = (const float*)d_in[0];
    const float* prev_w  = (const float*)d_in[1];
    const float* memory  = (const float*)d_in[2];
    const float* key_w   = (const float*)d_in[3];
    const float* key_b   = (const float*)d_in[4];
    const float* beta_w  = (const float*)d_in[5];
    const float* beta_b  = (const float*)d_in[6];
    const float* gate_w  = (const float*)d_in[7];
    const float* gate_b  = (const float*)d_in[8];
    const float* shift_w = (const float*)d_in[9];
    const float* shift_b = (const float*)d_in[10];
    const float* gamma_w = (const float*)d_in[11];
    const float* gamma_b = (const float*)d_in[12];
    // d_in[13..16] = erase_w/b, add_w/b — unused by outputs.

    float* out   = (float*)d_out;          // [0, B*N) weights, [B*N, +B*M) read_vec
    float* ws    = (float*)d_ws;
    float* e     = ws;                                   // B*N
    float* wp    = ws + (size_t)B_ * N_;                 // B*N
    float* kbuf  = ws + (size_t)2 * B_ * N_;             // B*M
    float* kn    = kbuf  + B_ * M_;                      // B
    float* beta  = kn    + B_;                           // B
    float* gate  = beta  + B_;                           // B
    float* gamma = gate  + B_;                           // B
    float* shift = gamma + B_;                           // 3*B
    float* sums  = shift + 3 * B_;                       // sumE[B], sumWp[B]
    float* sumE  = sums;
    float* sumWp = sums + B_;

    proj_kernel<<<B_, 128, 0, stream>>>(ctrl, key_w, key_b, beta_w, beta_b,
                                        gate_w, gate_b, shift_w, shift_b,
                                        gamma_w, gamma_b,
                                        kbuf, kn, beta, gate, gamma, shift,
                                        sumE, sumWp, out + (size_t)B_ * N_);

    content_kernel<<<dim3(N_ / ROWS_PER_CHUNK, B_), 256, 0, stream>>>(
        memory, kbuf, kn, beta, e, sumE);

    shiftpow_kernel<<<dim3(N_ / 4 / 256, B_), 256, 0, stream>>>(
        e, prev_w, sumE, gate, shift, gamma, wp, sumWp);

    read_kernel<<<dim3(N_ / ROWS_PER_CHUNK, B_), 256, 0, stream>>>(
        memory, wp, sumWp, out, out + (size_t)B_ * N_);
}

// Round 2
// 849.047 us; speedup vs baseline: 1.0637x; 1.0087x over previous
//
#include <hip/hip_runtime.h>
#include <math.h>

#define B_ 64
#define N_ 16384
#define M_ 128
#define C_ 1024
#define EPS_ 1e-16f

__device__ __forceinline__ float softplus_(float x) {
    return fmaxf(x, 0.f) + log1pf(expf(-fabsf(x)));
}

// ---------------------------------------------------------------------------
// Kernel A: parameter projections + zero-init of sums and read_vec output.
// One block per batch, 128 threads. erase/add are unused -> skipped.
// ---------------------------------------------------------------------------
__global__ void proj_kernel(const float* __restrict__ ctrl,
                            const float* __restrict__ key_w, const float* __restrict__ key_b,
                            const float* __restrict__ beta_w, const float* __restrict__ beta_b,
                            const float* __restrict__ gate_w, const float* __restrict__ gate_b,
                            const float* __restrict__ shift_w, const float* __restrict__ shift_b,
                            const float* __restrict__ gamma_w, const float* __restrict__ gamma_b,
                            float* __restrict__ k_out, float* __restrict__ kn_out,
                            float* __restrict__ beta_out, float* __restrict__ gate_out,
                            float* __restrict__ gamma_out, float* __restrict__ shift_out,
                            float* __restrict__ sumE, float* __restrict__ sumWp,
                            float* __restrict__ read_out)
{
    const int b = blockIdx.x;
    const int t = threadIdx.x;            // 128 threads, one per m
    const float* c = ctrl + (size_t)b * C_;

    // zero-init (replaces hipMemsetAsync calls)
    read_out[b * M_ + t] = 0.f;
    if (t == 0) { sumE[b] = 0.f; sumWp[b] = 0.f; }

    // key projection: 4-way ILP to break the serial FMA chain
    float a0 = 0.f, a1 = 0.f, a2 = 0.f, a3 = 0.f;
    for (int i = 0; i < C_; i += 4) {
        a0 = fmaf(c[i+0], key_w[(i+0) * M_ + t], a0);
        a1 = fmaf(c[i+1], key_w[(i+1) * M_ + t], a1);
        a2 = fmaf(c[i+2], key_w[(i+2) * M_ + t], a2);
        a3 = fmaf(c[i+3], key_w[(i+3) * M_ + t], a3);
    }
    float kv = tanhf(((a0 + a1) + (a2 + a3)) + key_b[t]);
    k_out[b * M_ + t] = kv;

    float p0 = 0, p1 = 0, p2 = 0, p3 = 0, p4 = 0, p5 = 0;
    for (int i = t; i < C_; i += 128) {
        float cv = c[i];
        p0 = fmaf(cv, beta_w[i],      p0);
        p1 = fmaf(cv, gate_w[i],      p1);
        p2 = fmaf(cv, gamma_w[i],     p2);
        p3 = fmaf(cv, shift_w[3*i+0], p3);
        p4 = fmaf(cv, shift_w[3*i+1], p4);
        p5 = fmaf(cv, shift_w[3*i+2], p5);
    }
    __shared__ float red[7][128];
    red[0][t] = p0; red[1][t] = p1; red[2][t] = p2;
    red[3][t] = p3; red[4][t] = p4; red[5][t] = p5;
    red[6][t] = kv * kv;
    __syncthreads();
    for (int s = 64; s > 0; s >>= 1) {
        if (t < s) {
            #pragma unroll
            for (int j = 0; j < 7; ++j) red[j][t] += red[j][t + s];
        }
        __syncthreads();
    }
    if (t == 0) {
        beta_out[b]  = softplus_(red[0][0] + beta_b[0]);
        gate_out[b]  = 1.f / (1.f + expf(-(red[1][0] + gate_b[0])));
        gamma_out[b] = 1.f + softplus_(red[2][0] + gamma_b[0]);
        float z0 = red[3][0] + shift_b[0];
        float z1 = red[4][0] + shift_b[1];
        float z2 = red[5][0] + shift_b[2];
        float mx = fmaxf(z0, fmaxf(z1, z2));
        float e0 = expf(z0 - mx), e1 = expf(z1 - mx), e2 = expf(z2 - mx);
        float inv = 1.f / (e0 + e1 + e2);
        shift_out[b*3+0] = e0 * inv;
        shift_out[b*3+1] = e1 * inv;
        shift_out[b*3+2] = e2 * inv;
        kn_out[b] = sqrtf(red[6][0]);
    }
}

// ---------------------------------------------------------------------------
// Kernel B: content addressing, 8-row x 8-lane layout, ASCENDING row order.
// Each wave covers 8 consecutive rows; lane (r,c) accumulates dot and
// sum-of-squares over 16 elements of row r (4 float4 windows 128B apart).
// Cross-lane reduce is only 3 shuffle levels; tail runs once per 8 rows.
// e = exp(beta/||k|| * d * rsqrt(q)); EPS negligible vs norms ~O(100).
// ---------------------------------------------------------------------------
#define ROWS_PER_CHUNK 1024
__global__ void content_kernel(const float* __restrict__ mem,
                               const float* __restrict__ k,
                               const float* __restrict__ kn,
                               const float* __restrict__ beta,
                               float* __restrict__ e_out,
                               float* __restrict__ sumE)
{
    const int b     = blockIdx.y;
    const int chunk = blockIdx.x;
    const int t     = threadIdx.x;        // 256 threads = 4 waves
    const int wave  = t >> 6;
    const int lane  = t & 63;
    const int r     = lane >> 3;          // 8 rows per wave
    const int c     = lane & 7;           // 8 lanes per row

    __shared__ float ks[M_];
    if (t < M_) ks[t] = k[b * M_ + t];
    __syncthreads();
    const float4 kf0 = reinterpret_cast<const float4*>(ks)[c];
    const float4 kf1 = reinterpret_cast<const float4*>(ks)[c + 8];
    const float4 kf2 = reinterpret_cast<const float4*>(ks)[c + 16];
    const float4 kf3 = reinterpret_cast<const float4*>(ks)[c + 24];
    const float bk = beta[b] / kn[b];

    const float* memb = mem + (size_t)b * N_ * M_;
    const int row0 = chunk * ROWS_PER_CHUNK + wave * 8 + r;

    float eacc = 0.f;
    #pragma unroll 2
    for (int tile = 0; tile < 32; ++tile) {
        const int row = row0 + tile * 32;
        const float4* mrow = reinterpret_cast<const float4*>(memb + (size_t)row * M_);
        float4 m;
        m = mrow[c];
        float d = m.x*kf0.x + m.y*kf0.y + m.z*kf0.z + m.w*kf0.w;
        float q = m.x*m.x + m.y*m.y + m.z*m.z + m.w*m.w;
        m = mrow[c + 8];
        d += m.x*kf1.x + m.y*kf1.y + m.z*kf1.z + m.w*kf1.w;
        q += m.x*m.x + m.y*m.y + m.z*m.z + m.w*m.w;
        m = mrow[c + 16];
        d += m.x*kf2.x + m.y*kf2.y + m.z*kf2.z + m.w*kf2.w;
        q += m.x*m.x + m.y*m.y + m.z*m.z + m.w*m.w;
        m = mrow[c + 24];
        d += m.x*kf3.x + m.y*kf3.y + m.z*kf3.z + m.w*kf3.w;
        q += m.x*m.x + m.y*m.y + m.z*m.z + m.w*m.w;
        // butterfly over the 8 c-lanes (xor 1,2,4 stays inside the group)
        d += __shfl_xor(d, 1, 64);  q += __shfl_xor(q, 1, 64);
        d += __shfl_xor(d, 2, 64);  q += __shfl_xor(q, 2, 64);
        d += __shfl_xor(d, 4, 64);  q += __shfl_xor(q, 4, 64);
        const float ev = __expf(bk * d * rsqrtf(q));
        if (c == 0) {
            e_out[(size_t)b * N_ + row] = ev;
            eacc += ev;
        }
    }
    __shared__ float red[256];
    red[t] = eacc;
    __syncthreads();
    for (int s = 128; s > 0; s >>= 1) {
        if (t < s) red[t] += red[t + s];
        __syncthreads();
    }
    if (t == 0) atomicAdd(&sumE[b], red[0]);
}

// ---------------------------------------------------------------------------
// Kernel C: gated interpolation + circular 3-tap shift + sharpen (pow).
// float4-vectorized: each thread produces 4 outputs; edge neighbors via
// two extra scalar loads (L1/L2 hits).
// ---------------------------------------------------------------------------
__global__ void shiftpow_kernel(const float* __restrict__ e,
                                const float* __restrict__ prev,
                                const float* __restrict__ sumE,
                                const float* __restrict__ gate,
                                const float* __restrict__ shift,
                                const float* __restrict__ gamma,
                                float* __restrict__ wp_out,
                                float* __restrict__ sumWp)
{
    const int b = blockIdx.y;
    const int i = blockIdx.x * 256 + threadIdx.x;   // float4 index over N/4
    const float invE = 1.f / sumE[b];               // jax softmax: no eps in denom
    const float g    = gate[b];
    const float gi   = g * invE;
    const float om   = 1.f - g;
    const float s0 = shift[b*3+0], s1 = shift[b*3+1], s2 = shift[b*3+2];
    const float gam = gamma[b];
    const float* eb = e    + (size_t)b * N_;
    const float* pb = prev + (size_t)b * N_;

    const float4 ec = reinterpret_cast<const float4*>(eb)[i];
    const float4 pc = reinterpret_cast<const float4*>(pb)[i];
    const int il = (i == 0)          ? N_ - 1 : 4*i - 1;   // wrap left
    const int ir = (i == N_/4 - 1)   ? 0      : 4*i + 4;   // wrap right
    const float wl = gi*eb[il] + om*pb[il];
    const float w0 = gi*ec.x  + om*pc.x;
    const float w1 = gi*ec.y  + om*pc.y;
    const float w2 = gi*ec.z  + om*pc.z;
    const float w3 = gi*ec.w  + om*pc.w;
    const float wr = gi*eb[ir] + om*pb[ir];

    float4 o;
    o.x = powf(s0*wl + s1*w0 + s2*w1, gam);
    o.y = powf(s0*w0 + s1*w1 + s2*w2, gam);
    o.z = powf(s0*w1 + s1*w2 + s2*w3, gam);
    o.w = powf(s0*w2 + s1*w3 + s2*wr, gam);
    reinterpret_cast<float4*>(wp_out + (size_t)b * N_)[i] = o;

    __shared__ float red[256];
    red[threadIdx.x] = (o.x + o.y) + (o.z + o.w);
    __syncthreads();
    for (int s = 128; s > 0; s >>= 1) {
        if (threadIdx.x < s) red[threadIdx.x] += red[threadIdx.x + s];
        __syncthreads();
    }
    if (threadIdx.x == 0) atomicAdd(&sumWp[b], red[0]);
}

// ---------------------------------------------------------------------------
// Kernel D (fused normalize + read): stages raw wp for the chunk in LDS and
// writes the normalized weights output during staging; accumulates
// sum(wp_n * mem_n) per lane, scales by 1/(sumWp+eps) at the end, LDS-reduces
// across the 8 row-groups, atomicAdd partial into read_vec.
//
// Row loop runs DESCENDING: content_kernel streamed each 512KB chunk
// ascending, so at read time the Infinity Cache (256 MiB vs 512 MiB tensor)
// holds the tail half of every chunk. Reading tail-first converts those
// lines into L3 hits instead of the LRU-worst-case 0% of same-order re-read.
// ---------------------------------------------------------------------------
__global__ void read_kernel(const float* __restrict__ mem,
                            const float* __restrict__ wp,
                            const float* __restrict__ sumWp,
                            float* __restrict__ out_w,
                            float* __restrict__ read_out)
{
    const int b     = blockIdx.y;
    const int chunk = blockIdx.x;
    const int t     = threadIdx.x;        // 256
    const int wave  = t >> 6;
    const int lane  = t & 63;
    const int half  = lane >> 5;
    const int sub   = lane & 31;
    const float inv = 1.f / (sumWp[b] + EPS_);

    __shared__ float wtile[ROWS_PER_CHUNK];
    {
        const float4 v = reinterpret_cast<const float4*>(
            wp + (size_t)b * N_ + chunk * ROWS_PER_CHUNK)[t];
        reinterpret_cast<float4*>(wtile)[t] = v;
        float4 o;
        o.x = v.x * inv; o.y = v.y * inv; o.z = v.z * inv; o.w = v.w * inv;
        reinterpret_cast<float4*>(
            out_w + (size_t)b * N_ + chunk * ROWS_PER_CHUNK)[t] = o;   // fused normalize
    }
    __syncthreads();

    const float* memb = mem + (size_t)b * N_ * M_;
    const int rowbase = chunk * ROWS_PER_CHUNK + wave * 2 + half;
    const int lbase   = wave * 2 + half;

    float4 acc = make_float4(0.f, 0.f, 0.f, 0.f);
    #pragma unroll 4
    for (int i = ROWS_PER_CHUNK / 8 - 1; i >= 0; --i) {   // descending: hit L3 tails first
        const int n  = rowbase + i * 8;
        const float wn = wtile[lbase + i * 8];            // LDS broadcast
        const float4 m4 = reinterpret_cast<const float4*>(memb + (size_t)n * M_)[sub];
        acc.x = fmaf(wn, m4.x, acc.x);
        acc.y = fmaf(wn, m4.y, acc.y);
        acc.z = fmaf(wn, m4.z, acc.z);
        acc.w = fmaf(wn, m4.w, acc.w);
    }
    acc.x *= inv; acc.y *= inv; acc.z *= inv; acc.w *= inv;

    __shared__ float red[8][32][4];
    const int g = wave * 2 + half;
    red[g][sub][0] = acc.x; red[g][sub][1] = acc.y;
    red[g][sub][2] = acc.z; red[g][sub][3] = acc.w;
    __syncthreads();
    if (t < M_) {
        const int m = t, s2 = m >> 2, cc = m & 3;
        float s = 0.f;
        #pragma unroll
        for (int gg = 0; gg < 8; ++gg) s += red[gg][s2][cc];
        atomicAdd(&read_out[b * M_ + m], s);
    }
}

// ---------------------------------------------------------------------------
extern "C" void kernel_launch(void* const* d_in, const int* in_sizes, int n_in,
                              void* d_out, int out_size, void* d_ws, size_t ws_size,
                              hipStream_t stream) {
    const float* ctrl    = (const float*)d_in[0];
    const float* prev_w  = (const float*)d_in[1];
    const float* memory  = (const float*)d_in[2];
    const float* key_w   = (const float*)d_in[3];
    const float* key_b   = (const float*)d_in[4];
    const float* beta_w  = (const float*)d_in[5];
    const float* beta_b  = (const float*)d_in[6];
    const float* gate_w  = (const float*)d_in[7];
    const float* gate_b  = (const float*)d_in[8];
    const float* shift_w = (const float*)d_in[9];
    const float* shift_b = (const float*)d_in[10];
    const float* gamma_w = (const float*)d_in[11];
    const float* gamma_b = (const float*)d_in[12];
    // d_in[13..16] = erase_w/b, add_w/b — unused by outputs.

    float* out   = (float*)d_out;          // [0, B*N) weights, [B*N, +B*M) read_vec
    float* ws    = (float*)d_ws;
    float* e     = ws;                                   // B*N
    float* wp    = ws + (size_t)B_ * N_;                 // B*N
    float* kbuf  = ws + (size_t)2 * B_ * N_;             // B*M
    float* kn    = kbuf  + B_ * M_;                      // B
    float* beta  = kn    + B_;                           // B
    float* gate  = beta  + B_;                           // B
    float* gamma = gate  + B_;                           // B
    float* shift = gamma + B_;                           // 3*B
    float* sums  = shift + 3 * B_;                       // sumE[B], sumWp[B]
    float* sumE  = sums;
    float* sumWp = sums + B_;

    proj_kernel<<<B_, 128, 0, stream>>>(ctrl, key_w, key_b, beta_w, beta_b,
                                        gate_w, gate_b, shift_w, shift_b,
                                        gamma_w, gamma_b,
                                        kbuf, kn, beta, gate, gamma, shift,
                                        sumE, sumWp, out + (size_t)B_ * N_);

    content_kernel<<<dim3(N_ / ROWS_PER_CHUNK, B_), 256, 0, stream>>>(
        memory, kbuf, kn, beta, e, sumE);

    shiftpow_kernel<<<dim3(N_ / 4 / 256, B_), 256, 0, stream>>>(
        e, prev_w, sumE, gate, shift, gamma, wp, sumWp);

    read_kernel<<<dim3(N_ / ROWS_PER_CHUNK, B_), 256, 0, stream>>>(
        memory, wp, sumWp, out, out + (size_t)B_ * N_);
}